// Round 15
// baseline (5413.136 us; speedup 1.0000x reference)
//
#include <hip/hip_runtime.h>
#include <cstddef>

using bf16x8 = __attribute__((ext_vector_type(8))) short;
using f32x4  = __attribute__((ext_vector_type(4))) float;

constexpr int Bb = 128;
constexpr int Tt = 256;
constexpr int Hh = 1024;
constexpr int Oo = 64;
constexpr int NBLK = 100;         // 32 H1 + 16 P2 + 16 PG + 32 H2U + 2 PO + 2 ZO
constexpr int FLAG_STRIDE = 32;   // dwords -> 128B between flags
constexpr int RS = 1048;          // LDS row stride in shorts (bank-spread, proven)

// ring depths
constexpr int R_H1 = 8;
constexpr int R_H2 = 16;
constexpr int R_PP = 6;
constexpr int R_PO = 16;

// flag group bases
constexpr int FH1 = 0;    // 32 slots (bid 0-31)
constexpr int FP2 = 32;   // 16 slots (bid 32-47)
constexpr int FPG = 48;   // 16 slots (bid 48-63)
constexpr int FH2 = 64;   // 32 slots (bid 64-95)
constexpr int FPO = 96;   // 2 slots  (bid 96-97)
constexpr int FZO = 98;   // 2 slots  (bid 98-99)

__device__ __forceinline__ float bf2f(short s) {
  unsigned int u = ((unsigned int)(unsigned short)s) << 16;
  float f;
  __builtin_memcpy(&f, &u, 4);
  return f;
}
__device__ __forceinline__ short f2bf(float f) {
  unsigned int u;
  __builtin_memcpy(&u, &f, 4);
  u += 0x7fffu + ((u >> 16) & 1u);  // round-to-nearest-even
  return (short)(u >> 16);
}
__device__ __forceinline__ bf16x8 as_bf(int4 v) {
  union { int4 i; bf16x8 b; } u; u.i = v; return u.b;
}
__device__ __forceinline__ float ldf(const float* p) {
  return __hip_atomic_load((float*)p, __ATOMIC_RELAXED, __HIP_MEMORY_SCOPE_AGENT);
}
__device__ __forceinline__ void stf(float* p, float v) {
  __hip_atomic_store(p, v, __ATOMIC_RELAXED, __HIP_MEMORY_SCOPE_AGENT);
}
__device__ __forceinline__ unsigned ldu(const unsigned* p) {
  return __hip_atomic_load((unsigned*)p, __ATOMIC_RELAXED, __HIP_MEMORY_SCOPE_AGENT);
}

// Agent-scope (sc1) coherent 16B load — LLC-coherent (cross-XCD state reads).
#define LD16A(d, p) asm volatile("global_load_dwordx4 %0, %1, off sc1" \
                                 : "=v"(d) : "v"((const void*)(p)))

// 512-thread staging of one 32-row x 1024-col bf16 slab (8 loads/thread).
__device__ __forceinline__ void stage_issue(int4 (&r)[8], const short* src, int tid) {
  const int row = tid >> 4;          // 0..31
  const int c0  = (tid & 15) * 8;    // shorts
  const short* gp = src + (size_t)row * Hh + c0;
#pragma unroll
  for (int j = 0; j < 8; ++j) LD16A(r[j], gp + j * 128);
}
__device__ __forceinline__ void stage_write(short* dstAs, int4 (&r)[8], int tid) {
  const int row = tid >> 4;
  const int c0  = (tid & 15) * 8;
  short* lp = dstAs + row * RS + c0;
  asm volatile("s_waitcnt vmcnt(0)" ::: "memory");
#pragma unroll
  for (int j = 0; j < 8; ++j) *(int4*)(lp + j * 128) = r[j];
}
__device__ __forceinline__ void stage_chunk(short* dstAs, const short* src, int tid) {
  int4 r[8];
  stage_issue(r, src, tid);
  stage_write(dstAs, r, tid);
}

// Load this wave's 16-col weight slice into 128 VGPRs (once, before t-loop).
__device__ __forceinline__ void loadW(int4 (&w)[32], const short* B, size_t st,
                                      int lm, int q) {
  const short* bp = B + (size_t)lm * st + q * 8;
#pragma unroll
  for (int c = 0; c < 32; ++c) w[c] = *(const int4*)(bp + c * 32);
}

// K=1024 pass over a 32-row As chunk: 2 row-frags, 1 col-frag, W from regs.
__device__ __forceinline__ void passW2(const short* As32, int lm, int q,
    const int4 (&w)[32], f32x4& acc0, f32x4& acc1) {
  const short* ap0 = As32 + lm * RS + q * 8;
  const short* ap1 = ap0 + 16 * RS;
#pragma unroll
  for (int c = 0; c < 32; ++c) {
    const bf16x8 a0 = as_bf(*(const int4*)(ap0 + c * 32));
    const bf16x8 a1 = as_bf(*(const int4*)(ap1 + c * 32));
    const bf16x8 b  = as_bf(w[c]);
    acc0 = __builtin_amdgcn_mfma_f32_16x16x32_bf16(a0, b, acc0, 0, 0, 0);
    acc1 = __builtin_amdgcn_mfma_f32_16x16x32_bf16(a1, b, acc1, 0, 0, 0);
  }
}

// Dataflow sync: poll one producer group's flags until all >= gen (wave 0).
__device__ __forceinline__ void poll_ge(const unsigned* flags, int base,
                                        int mask, unsigned gen) {
  const unsigned* f = flags + (size_t)(base + (threadIdx.x & mask)) * FLAG_STRIDE;
  while (!__all(ldu(f) >= gen))
    __builtin_amdgcn_s_sleep(2);
}

// Release: all waves drain, block-sync, tid0 posts to the given flag slot.
#define POST_FLAG(SLOT, GEN) do {                                          \
    asm volatile("s_waitcnt vmcnt(0) lgkmcnt(0)" ::: "memory");            \
    __syncthreads();                                                       \
    if (tid == 0)                                                          \
      __hip_atomic_store(p.flags + (size_t)(SLOT) * FLAG_STRIDE,           \
                         (unsigned)(GEN),                                  \
                         __ATOMIC_RELAXED, __HIP_MEMORY_SCOPE_AGENT);      \
  } while (0)

#define ST_BF16_PAIR(BASE, ROW, COL, HV) do {                              \
    const int _ov = __shfl_xor((int)(unsigned short)(HV), 1, 64);          \
    if ((lm & 1) == 0) {                                                   \
      const unsigned _pk = (unsigned)(unsigned short)(HV) | ((unsigned)_ov << 16); \
      __hip_atomic_store((unsigned*)((BASE) + (size_t)(ROW) * Hh + (COL)), _pk, \
                         __ATOMIC_RELAXED, __HIP_MEMORY_SCOPE_AGENT);      \
    } } while (0)

struct RP {
  short *h1ring;                    // 8  slots of [Bb x Hh] bf16
  short *h2ring;                    // 16 slots of [Bb x Hh] bf16
  float *h2f;                       // h2 f32 master (block-local tiles)
  float *pre2f;                     // 6 slots
  float *pg1f;                      // 6 slots
  float *po1f;                      // 16 slots of [Bb x Oo]
  const short* prex;
  const short *whh1, *wih2, *whh2, *wg, *wo1, *wo2;
  const float *b_ih2, *b_hh2, *bg, *bo1, *bo2;
  float* out;
  unsigned* flags;
};

// FAT-BLOCK edition, SPILL-FIXED: amdgpu_waves_per_eu(2,2) tells the
// allocator occupancy is exactly 2 waves/EU (LDS pins 1 block/CU anyway)
// -> 256-VGPR budget -> w[32] stays register-resident (r14 spilled at 128).
// Dataflow graph = r8/r9 (twice-verified), flag groups remapped.
__global__ void __launch_bounds__(512, 1)
__attribute__((amdgpu_waves_per_eu(2, 2))) rnn_kernel(RP p) {
  __shared__ short As[64 * RS];     // 134144 B (two 32-row chunks)
  __shared__ float zbuf[4096];      // 16 KB H2U z-exchange (4 col-halves)
  const int tid = threadIdx.x;
  const int lane = tid & 63;
  const int wv = tid >> 6;          // 0..7
  const int lm = lane & 15;
  const int q = lane >> 4;
  const int bid = blockIdx.x;

  const size_t HS = (size_t)Bb * Hh;
  const f32x4 z4 = {0.f, 0.f, 0.f, 0.f};
  int4 w[32];                       // this wave's weight slice (128 VGPR)

  if (bid < 32) {                      // ===== H1: 4rg x 8cg, 32r x 128c =====
    const int rg = bid >> 3, cg = bid & 7;
    const int mb = rg * 32, cb = cg * 128;
    const int cw = cb + wv * 16;
    loadW(w, p.whh1 + (size_t)cw * Hh, Hh, lm, q);
    for (int t = 0; t < Tt; ++t) {
      short prs[2][4];
      const short* pr = p.prex + (size_t)t * HS;
#pragma unroll
      for (int rf = 0; rf < 2; ++rf)
#pragma unroll
        for (int r = 0; r < 4; ++r)
          prs[rf][r] = pr[(size_t)(mb + rf * 16 + q * 4 + r) * Hh + cw + lm];
      if (tid < 64 && t >= 1) poll_ge(p.flags, FH1 + rg * 8, 7, (unsigned)t);
      __syncthreads();
      const short* h1prev = p.h1ring + (size_t)((t + R_H1 - 1) % R_H1) * HS;
      stage_chunk(As, h1prev + (size_t)mb * Hh, tid);
      __syncthreads();
      f32x4 a0 = z4, a1 = z4;
      passW2(As, lm, q, w, a0, a1);
      if (tid < 64 && t >= 8) {      // overwrite gates, hidden post-pass
        poll_ge(p.flags, FP2 + (rg >> 1) * 8, 7, (unsigned)(t - 7));
        poll_ge(p.flags, FPG + (rg >> 1) * 8, 7, (unsigned)(t - 7));
        poll_ge(p.flags, FPO + (rg >> 1), 0, (unsigned)(t - 7));
      }
      __syncthreads();
      short* h1out = p.h1ring + (size_t)(t % R_H1) * HS;
#pragma unroll
      for (int rf = 0; rf < 2; ++rf)
#pragma unroll
        for (int r = 0; r < 4; ++r) {
          const int row = mb + rf * 16 + q * 4 + r;
          const float z = rf ? a1[r] : a0[r];
          const short hv = f2bf(tanhf(z + bf2f(prs[rf][r])));
          ST_BF16_PAIR(h1out, row, cw + lm, hv);
        }
      POST_FLAG(FH1 + bid, t + 1);
    }
  } else if (bid < 64) {               // ===== P2 / PG: 2rg x 8cg, 64r x 128c =====
    const bool isP2 = (bid < 48);
    const int g = bid - (isP2 ? 32 : 48);     // 0..15
    const int rgp = g >> 3, cg = g & 7;
    const int mb = rgp * 64, cb = cg * 128;
    const int cw = cb + wv * 16;
    float bias;
    if (isP2) {
      bias = p.b_ih2[cw + lm] + p.b_hh2[cw + lm];
      loadW(w, p.wih2 + (size_t)cw * Hh, Hh, lm, q);
    } else {
      bias = p.bg[cw + lm];
      loadW(w, p.wg + (size_t)cw * (2 * Hh), 2 * Hh, lm, q);
    }
    const int fslot = (isP2 ? FP2 : FPG) + g;
    const int gslot = FH2 + rgp * 16 + cg * 2;   // 2 H2U readers of our cols
    const int glag = isP2 ? 5 : 4;
    for (int t = 0; t < Tt; ++t) {
      if (tid < 64) poll_ge(p.flags, FH1 + rgp * 16, 15, (unsigned)(t + 1));
      __syncthreads();
      const short* h1cur = p.h1ring + (size_t)(t % R_H1) * HS;
      stage_chunk(As, h1cur + (size_t)mb * Hh, tid);
      __syncthreads();
      int4 rB[8];
      stage_issue(rB, h1cur + (size_t)(mb + 32) * Hh, tid);
      f32x4 acc[4];
      acc[0] = acc[1] = acc[2] = acc[3] = (f32x4){bias, bias, bias, bias};
      passW2(As, lm, q, w, acc[0], acc[1]);        // B-chunk in flight
      stage_write(As + 32 * RS, rB, tid);
      __syncthreads();
      passW2(As + 32 * RS, lm, q, w, acc[2], acc[3]);
      if (tid < 64 && t >= R_PP) poll_ge(p.flags, gslot, 1, (unsigned)(t - glag));
      __syncthreads();
      float* dst = (isP2 ? p.pre2f : p.pg1f) + (size_t)(t % R_PP) * HS;
#pragma unroll
      for (int rf = 0; rf < 4; ++rf)
#pragma unroll
        for (int r = 0; r < 4; ++r) {
          const int row = mb + rf * 16 + q * 4 + r;
          stf(dst + (size_t)row * Hh + cw + lm, acc[rf][r]);
        }
      POST_FLAG(fslot, t + 1);
    }
  } else if (bid < 96) {               // ===== H2U: 2rg x 16cg, 64r x 64c =====
    const int g = bid - 64;                   // 0..31
    const int rgh = g >> 4, cgh = g & 15;
    const int mb = rgh * 64, cb = cgh * 64;
    const int m = wv >> 2;             // 0: z2 (whh2), 1: zg (wg2)
    const int ch = wv & 3;             // col quarter (16 cols)
    const int cw = cb + ch * 16;
    const int fp2slot = FP2 + rgh * 8 + (cgh >> 1);
    const int fpgslot = FPG + rgh * 8 + (cgh >> 1);
    if (m == 0) loadW(w, p.whh2 + (size_t)cw * Hh, Hh, lm, q);
    else        loadW(w, p.wg + Hh + (size_t)cw * (2 * Hh), 2 * Hh, lm, q);
    for (int s = 0; s < Tt; ++s) {
      if (tid < 64) {
        poll_ge(p.flags, fp2slot, 0, (unsigned)(s + 1));
        if (s >= 1) {
          poll_ge(p.flags, fpgslot, 0, (unsigned)s);
          poll_ge(p.flags, FH2 + rgh * 16, 15, (unsigned)s);
        }
      }
      __syncthreads();
      const short* h2prev = p.h2ring + (size_t)((s + R_H2 - 1) % R_H2) * HS;
      stage_chunk(As, h2prev + (size_t)mb * Hh, tid);
      __syncthreads();
      int4 rB[8];
      stage_issue(rB, h2prev + (size_t)(mb + 32) * Hh, tid);
      f32x4 acc[4];
      acc[0] = acc[1] = acc[2] = acc[3] = z4;
      passW2(As, lm, q, w, acc[0], acc[1]);        // B-chunk in flight
      stage_write(As + 32 * RS, rB, tid);
      __syncthreads();
      float p2v[4][4], pg1v[4][4], hpv[4][4];
      if (m == 0) {                    // operand loads hide under pass-B
        const float* pre2s = p.pre2f + (size_t)(s % R_PP) * HS;
        const float* pg1s  = p.pg1f + (size_t)((s + R_PP - 1) % R_PP) * HS;
#pragma unroll
        for (int rf = 0; rf < 4; ++rf)
#pragma unroll
          for (int r = 0; r < 4; ++r) {
            const size_t idx = (size_t)(mb + rf * 16 + q * 4 + r) * Hh + cw + lm;
            p2v[rf][r] = ldf(pre2s + idx);
            pg1v[rf][r] = (s > 0) ? ldf(pg1s + idx) : 0.f;
            hpv[rf][r] = p.h2f[idx];   // block-local plain RW
          }
      }
      passW2(As + 32 * RS, lm, q, w, acc[2], acc[3]);
      if (m == 1) {                    // publish zg to the matching z2 wave
        float* zb = zbuf + ch * 1024;
#pragma unroll
        for (int rf = 0; rf < 4; ++rf)
#pragma unroll
          for (int r = 0; r < 4; ++r)
            zb[(rf * 4 + r) * 64 + lane] = acc[rf][r];
      }
      if (tid < 64 && s >= R_H2) poll_ge(p.flags, FZO + rgh, 0, (unsigned)(s - 15));
      __syncthreads();
      if (m == 0) {
        const float* zb = zbuf + ch * 1024;
        short* h2out = p.h2ring + (size_t)(s % R_H2) * HS;
#pragma unroll
        for (int rf = 0; rf < 4; ++rf)
#pragma unroll
          for (int r = 0; r < 4; ++r) {
            const int row = mb + rf * 16 + q * 4 + r;
            const size_t idx = (size_t)row * Hh + cw + lm;
            const float zg = zb[(rf * 4 + r) * 64 + lane];
            const float u = (s == 0) ? 1.f
                : 1.f / (1.f + expf(-(zg + pg1v[rf][r])));
            const float hn = tanhf(acc[rf][r] + p2v[rf][r]);
            const float nv = fmaf(u, hn - hpv[rf][r], hpv[rf][r]);
            p.h2f[idx] = nv;
            const short hv = f2bf(nv);
            ST_BF16_PAIR(h2out, row, cw + lm, hv);
          }
      }
      POST_FLAG(FH2 + g, s + 1);
    }
  } else if (bid < 98) {               // ===== PO: 2 blocks, 64r x 64c =====
    const int g = bid - 96;
    const int mb = g * 64;
    const int cw = (wv & 3) * 16;
    const bool act = (wv < 4);
    const float bias = p.bo1[cw + lm];
    loadW(w, p.wo1 + (size_t)cw * Hh, Hh, lm, q);
    for (int t = 0; t < Tt; ++t) {
      if (tid < 64) poll_ge(p.flags, FH1 + g * 16, 15, (unsigned)(t + 1));
      __syncthreads();
      const short* h1cur = p.h1ring + (size_t)(t % R_H1) * HS;
      stage_chunk(As, h1cur + (size_t)mb * Hh, tid);
      __syncthreads();
      int4 rB[8];
      stage_issue(rB, h1cur + (size_t)(mb + 32) * Hh, tid);
      f32x4 acc[4];
      acc[0] = acc[1] = acc[2] = acc[3] = (f32x4){bias, bias, bias, bias};
      if (act) passW2(As, lm, q, w, acc[0], acc[1]);
      stage_write(As + 32 * RS, rB, tid);
      __syncthreads();
      if (act) passW2(As + 32 * RS, lm, q, w, acc[2], acc[3]);
      if (tid < 64 && t >= R_PO) poll_ge(p.flags, FZO + g, 0, (unsigned)(t - 15));
      __syncthreads();
      if (act) {
        float* dst = p.po1f + (size_t)(t % R_PO) * (Bb * Oo);
#pragma unroll
        for (int rf = 0; rf < 4; ++rf)
#pragma unroll
          for (int r = 0; r < 4; ++r) {
            const int row = mb + rf * 16 + q * 4 + r;
            stf(dst + (size_t)row * Oo + cw + lm, tanhf(acc[rf][r]));
          }
      }
      POST_FLAG(FPO + g, t + 1);
    }
  } else {                             // ===== ZO: 2 blocks, 64r x 64c =====
    const int g = bid - 98;
    const int mb = g * 64;
    const int cw = (wv & 3) * 16;
    const bool act = (wv < 4);
    const float bias = p.bo2[cw + lm];
    loadW(w, p.wo2 + (size_t)cw * Hh, Hh, lm, q);
    for (int ot = 0; ot < Tt; ++ot) {
      if (tid < 64) {
        poll_ge(p.flags, FH2 + g * 16, 15, (unsigned)(ot + 1));
        poll_ge(p.flags, FPO + g, 0, (unsigned)(ot + 1));
      }
      __syncthreads();
      float pv[4][4];
      if (act) {
        const float* po1s = p.po1f + (size_t)(ot % R_PO) * (Bb * Oo);
#pragma unroll
        for (int rf = 0; rf < 4; ++rf)
#pragma unroll
          for (int r = 0; r < 4; ++r)
            pv[rf][r] = ldf(po1s + (size_t)(mb + rf * 16 + q * 4 + r) * Oo + cw + lm);
      }
      const short* h2cur = p.h2ring + (size_t)(ot % R_H2) * HS;
      stage_chunk(As, h2cur + (size_t)mb * Hh, tid);
      __syncthreads();
      int4 rB[8];
      stage_issue(rB, h2cur + (size_t)(mb + 32) * Hh, tid);
      f32x4 acc[4];
      acc[0] = acc[1] = acc[2] = acc[3] = (f32x4){bias, bias, bias, bias};
      if (act) passW2(As, lm, q, w, acc[0], acc[1]);
      stage_write(As + 32 * RS, rB, tid);
      __syncthreads();
      if (act) {
        passW2(As + 32 * RS, lm, q, w, acc[2], acc[3]);
#pragma unroll
        for (int rf = 0; rf < 4; ++rf)
#pragma unroll
          for (int r = 0; r < 4; ++r) {
            const int row = mb + rf * 16 + q * 4 + r;
            p.out[(size_t)row * (Tt * Oo) + (size_t)ot * Oo + cw + lm] =
                pv[rf][r] + tanhf(acc[rf][r]);
          }
      }
      POST_FLAG(FZO + g, ot + 1);
    }
  }
}

// pre_x[t][b][j] = x[b,t,:] @ W_ih1[j,:] + b_ih1[j] + b_hh1[j]  (stored bf16)
__global__ void __launch_bounds__(256) prex_kernel(
    const float* __restrict__ x, const float* __restrict__ wih1,
    const float* __restrict__ b_ih1, const float* __restrict__ b_hh1,
    short* __restrict__ prex) {
  const int tid = threadIdx.x;
  const int lane = tid & 63;
  const int wv = tid >> 6;
  const int lm = lane & 15;
  const int q = lane >> 4;
  const int bm = blockIdx.x >> 4;
  const int bn = blockIdx.x & 15;
  const int rowbase = bm * 64;
  const int col = bn * 64 + wv * 16 + lm;

  const f32x4 z4 = {0.f, 0.f, 0.f, 0.f};
  f32x4 acc[4];
#pragma unroll
  for (int mt = 0; mt < 4; ++mt) acc[mt] = z4;

#pragma unroll
  for (int kc = 0; kc < 2; ++kc) {
    const float* bp = wih1 + col * 64 + kc * 32 + q * 8;
    bf16x8 bf;
#pragma unroll
    for (int j = 0; j < 8; ++j) bf[j] = f2bf(bp[j]);
#pragma unroll
    for (int mt = 0; mt < 4; ++mt) {
      const float* ap = x + (size_t)(rowbase + mt * 16 + lm) * 64 + kc * 32 + q * 8;
      bf16x8 af;
#pragma unroll
      for (int j = 0; j < 8; ++j) af[j] = f2bf(ap[j]);
      acc[mt] = __builtin_amdgcn_mfma_f32_16x16x32_bf16(af, bf, acc[mt], 0, 0, 0);
    }
  }
  const float bia = b_ih1[col] + b_hh1[col];
#pragma unroll
  for (int mt = 0; mt < 4; ++mt) {
#pragma unroll
    for (int r = 0; r < 4; ++r) {
      const int row = rowbase + mt * 16 + q * 4 + r;  // row = b*256 + t
      const int b  = row >> 8;
      const int tt = row & 255;
      prex[((size_t)tt * Bb + b) * Hh + col] = f2bf(acc[mt][r] + bia);
    }
  }
}

__global__ void conv_kernel(const float* __restrict__ s, short* __restrict__ d, int n) {
  int i = blockIdx.x * blockDim.x + threadIdx.x;
  const int stride = gridDim.x * blockDim.x;
  for (; i < n; i += stride) d[i] = f2bf(s[i]);
}

__global__ void init_kernel(short* h1ring, short* h2ring,
                            float* h2f, unsigned* flags) {
  const int i = blockIdx.x * blockDim.x + threadIdx.x;  // exactly 128*1024
  const size_t HS = (size_t)Bb * Hh;
  h1ring[(size_t)(R_H1 - 1) * HS + i] = 0;   // h1(-1) slot
  h2ring[(size_t)(R_H2 - 1) * HS + i] = 0;   // h2(-1) slot
  h2f[i] = 0.f;
  if (i < 256) flags[i * FLAG_STRIDE] = 0u;
}

extern "C" void kernel_launch(void* const* d_in, const int* in_sizes, int n_in,
                              void* d_out, int out_size, void* d_ws, size_t ws_size,
                              hipStream_t stream) {
  (void)in_sizes; (void)n_in; (void)out_size; (void)ws_size;
  const float* x      = (const float*)d_in[0];
  const float* W_ih1  = (const float*)d_in[1];
  const float* b_ih1  = (const float*)d_in[2];
  const float* W_hh1  = (const float*)d_in[3];
  const float* b_hh1  = (const float*)d_in[4];
  const float* W_ih2  = (const float*)d_in[5];
  const float* b_ih2  = (const float*)d_in[6];
  const float* W_hh2  = (const float*)d_in[7];
  const float* b_hh2  = (const float*)d_in[8];
  const float* Wg     = (const float*)d_in[9];
  const float* bg     = (const float*)d_in[10];
  const float* Wo1    = (const float*)d_in[11];
  const float* bo1    = (const float*)d_in[12];
  const float* Wo2    = (const float*)d_in[13];
  const float* bo2    = (const float*)d_in[14];

  char* ws = (char*)d_ws;
  size_t off = 0;
  auto alloc = [&](size_t bytes) -> void* {
    void* ptr = ws + off;
    off += (bytes + 255) & ~(size_t)255;
    return ptr;
  };
  short* whh1 = (short*)alloc((size_t)Hh * Hh * 2);
  short* wih2 = (short*)alloc((size_t)Hh * Hh * 2);
  short* whh2 = (short*)alloc((size_t)Hh * Hh * 2);
  short* wg   = (short*)alloc((size_t)Hh * 2 * Hh * 2);
  short* wo1  = (short*)alloc((size_t)Oo * Hh * 2);
  short* wo2  = (short*)alloc((size_t)Oo * Hh * 2);
  short* prex = (short*)alloc((size_t)Bb * Tt * Hh * 2);
  short* h1ring = (short*)alloc((size_t)R_H1 * Bb * Hh * 2);
  short* h2ring = (short*)alloc((size_t)R_H2 * Bb * Hh * 2);
  float* h2f  = (float*)alloc((size_t)Bb * Hh * 4);
  float* pre2f= (float*)alloc((size_t)R_PP * Bb * Hh * 4);
  float* pg1f = (float*)alloc((size_t)R_PP * Bb * Hh * 4);
  float* po1f = (float*)alloc((size_t)R_PO * Bb * Oo * 4);
  unsigned* flags = (unsigned*)alloc(256 * FLAG_STRIDE * 4);   // 32 KB

  conv_kernel<<<1024, 256, 0, stream>>>(W_hh1, whh1, Hh * Hh);
  conv_kernel<<<1024, 256, 0, stream>>>(W_ih2, wih2, Hh * Hh);
  conv_kernel<<<1024, 256, 0, stream>>>(W_hh2, whh2, Hh * Hh);
  conv_kernel<<<2048, 256, 0, stream>>>(Wg,    wg,   Hh * 2 * Hh);
  conv_kernel<<<256,  256, 0, stream>>>(Wo1,   wo1,  Oo * Hh);
  conv_kernel<<<256,  256, 0, stream>>>(Wo2,   wo2,  Oo * Hh);
  init_kernel<<<512, 256, 0, stream>>>(h1ring, h2ring, h2f, flags);
  prex_kernel<<<8192, 256, 0, stream>>>(x, W_ih1, b_ih1, b_hh1, prex);

  RP p;
  p.h1ring = h1ring; p.h2ring = h2ring;
  p.h2f = h2f; p.pre2f = pre2f; p.pg1f = pg1f; p.po1f = po1f;
  p.prex = prex;
  p.whh1 = whh1; p.wih2 = wih2; p.whh2 = whh2;
  p.wg = wg; p.wo1 = wo1; p.wo2 = wo2;
  p.b_ih2 = b_ih2; p.b_hh2 = b_hh2;
  p.bg = bg; p.bo1 = bo1; p.bo2 = bo2;
  p.out = (float*)d_out;
  p.flags = flags;

  rnn_kernel<<<NBLK, 512, 0, stream>>>(p);
}

// Round 16
// 2691.622 us; speedup vs baseline: 2.0111x; 2.0111x over previous
//
#include <hip/hip_runtime.h>
#include <cstddef>

using bf16x8 = __attribute__((ext_vector_type(8))) short;
using f32x4  = __attribute__((ext_vector_type(4))) float;

constexpr int Bb = 128;
constexpr int Tt = 256;
constexpr int Hh = 1024;
constexpr int Oo = 64;
constexpr int NBLK = 200;         // 64 H1 + 32 P2 + 32 PG + 64 H2U + 4 PO + 4 ZO
constexpr int FLAG_STRIDE = 32;   // dwords -> 128B between flags
constexpr int RS = 1048;          // LDS row stride in shorts (bank-spread, proven)

// ring depths
constexpr int R_H1 = 8;
constexpr int R_H2 = 16;
constexpr int R_PP = 6;
constexpr int R_PO = 16;

// flag group bases
constexpr int FH1 = 0;    // 64 slots (bid 0-63)
constexpr int FP2 = 64;   // 32 slots (bid 64-95)
constexpr int FPG = 96;   // 32 slots (bid 96-127)
constexpr int FPO = 128;  // 4 slots  (bid 192-195)
constexpr int FH2 = 160;  // 64 slots (bid 128-191)
constexpr int FZO = 224;  // 4 slots  (bid 196-199)

__device__ __forceinline__ float bf2f(short s) {
  unsigned int u = ((unsigned int)(unsigned short)s) << 16;
  float f;
  __builtin_memcpy(&f, &u, 4);
  return f;
}
__device__ __forceinline__ short f2bf(float f) {
  unsigned int u;
  __builtin_memcpy(&u, &f, 4);
  u += 0x7fffu + ((u >> 16) & 1u);  // round-to-nearest-even
  return (short)(u >> 16);
}
__device__ __forceinline__ bf16x8 as_bf(int4 v) {
  union { int4 i; bf16x8 b; } u; u.i = v; return u.b;
}
__device__ __forceinline__ float ldf(const float* p) {
  return __hip_atomic_load((float*)p, __ATOMIC_RELAXED, __HIP_MEMORY_SCOPE_AGENT);
}
__device__ __forceinline__ void stf(float* p, float v) {
  __hip_atomic_store(p, v, __ATOMIC_RELAXED, __HIP_MEMORY_SCOPE_AGENT);
}
__device__ __forceinline__ unsigned ldu(const unsigned* p) {
  return __hip_atomic_load((unsigned*)p, __ATOMIC_RELAXED, __HIP_MEMORY_SCOPE_AGENT);
}

// Agent-scope (sc1) coherent 16B load — LLC-coherent (cross-XCD state reads).
#define LD16A(d, p) asm volatile("global_load_dwordx4 %0, %1, off sc1" \
                                 : "=v"(d) : "v"((const void*)(p)))

// Stage one 32-row x 1024-col bf16 state slab into LDS (256 thr x 16 loads).
__device__ __forceinline__ void stage_chunk(short* dstAs, const short* src, int tid) {
  const int row = tid >> 3;          // 0..31
  const int c0  = (tid & 7) * 8;     // shorts
  const short* gp = src + (size_t)row * Hh + c0;
  short* lp = dstAs + row * RS + c0;
  int4 r0[16];
#pragma unroll
  for (int j = 0; j < 16; ++j) LD16A(r0[j], gp + j * 64);
  asm volatile("s_waitcnt vmcnt(0)" ::: "memory");
#pragma unroll
  for (int j = 0; j < 16; ++j) *(int4*)(lp + j * 64) = r0[j];
}

// Load this wave's 16-col weight slice into 128 VGPRs (once, before t-loop).
// Layout matches MFMA B-operand: lane holds W[col=base+lm][k=q*8+c*32+0..7].
__device__ __forceinline__ void loadW(int4 (&w)[32], const short* B, size_t st,
                                      int lm, int q) {
  const short* bp = B + (size_t)lm * st + q * 8;
#pragma unroll
  for (int c = 0; c < 32; ++c) w[c] = *(const int4*)(bp + c * 32);
}

// K=1024 pass over a 32-row As chunk: 2 row-frags, 1 col-frag, W from regs.
__device__ __forceinline__ void passW2(const short* As32, int lm, int q,
    const int4 (&w)[32], f32x4& acc0, f32x4& acc1) {
  const short* ap0 = As32 + lm * RS + q * 8;
  const short* ap1 = ap0 + 16 * RS;
#pragma unroll
  for (int c = 0; c < 32; ++c) {
    const bf16x8 a0 = as_bf(*(const int4*)(ap0 + c * 32));
    const bf16x8 a1 = as_bf(*(const int4*)(ap1 + c * 32));
    const bf16x8 b  = as_bf(w[c]);
    acc0 = __builtin_amdgcn_mfma_f32_16x16x32_bf16(a0, b, acc0, 0, 0, 0);
    acc1 = __builtin_amdgcn_mfma_f32_16x16x32_bf16(a1, b, acc1, 0, 0, 0);
  }
}

// Dataflow sync: poll one producer group's flags until all >= gen (wave 0).
__device__ __forceinline__ void poll_ge(const unsigned* flags, int base,
                                        int mask, unsigned gen) {
  const unsigned* f = flags + (size_t)(base + (threadIdx.x & mask)) * FLAG_STRIDE;
  while (!__all(ldu(f) >= gen))
    __builtin_amdgcn_s_sleep(2);
}

// Release: all waves drain, block-sync, tid0 posts to this block's flag slot.
#define POST_FLAG(SLOT, GEN) do {                                          \
    asm volatile("s_waitcnt vmcnt(0) lgkmcnt(0)" ::: "memory");            \
    __syncthreads();                                                       \
    if (tid == 0)                                                          \
      __hip_atomic_store(p.flags + (size_t)(SLOT) * FLAG_STRIDE,           \
                         (unsigned)(GEN),                                  \
                         __ATOMIC_RELAXED, __HIP_MEMORY_SCOPE_AGENT);      \
  } while (0)

#define ST_BF16_PAIR(BASE, ROW, COL, HV) do {                              \
    const int _ov = __shfl_xor((int)(unsigned short)(HV), 1, 64);          \
    if ((lm & 1) == 0) {                                                   \
      const unsigned _pk = (unsigned)(unsigned short)(HV) | ((unsigned)_ov << 16); \
      __hip_atomic_store((unsigned*)((BASE) + (size_t)(ROW) * Hh + (COL)), _pk, \
                         __ATOMIC_RELAXED, __HIP_MEMORY_SCOPE_AGENT);      \
    } } while (0)

struct RP {
  short *h1ring;                    // 8  slots of [Bb x Hh] bf16
  short *h2ring;                    // 16 slots of [Bb x Hh] bf16
  float *h2f;                       // h2 f32 master (block-local tiles)
  float *pre2f;                     // 6 slots
  float *pg1f;                      // 6 slots
  float *po1f;                      // 16 slots of [Bb x Oo]
  const short* prex;
  const short *whh1, *wih2, *whh2, *wg, *wo1, *wo2;
  const float *b_ih2, *b_hh2, *bg, *bo1, *bo2;
  float* out;
  unsigned* flags;
};

// REGISTER-RESIDENT-WEIGHTS dataflow (r8, best measured: 2560us steady).
// Each wave owns 16 output cols; its 32KB weight slice lives in 128 VGPRs
// for all 256 steps (zero per-step B-feed). Dataflow graph ref-verified:
//   H1(t)  <- FH1>=t; [t>=8]  FP2,FPG >= t-7, FPO >= t-7      (h1 ring 8)
//   P2(t)  <- FH1>=t+1; [t>=6] FH2 >= t-5                     (pre2 ring 6)
//   PG(t)  <- FH1>=t+1; [t>=6] FH2 >= t-4                     (pg1 ring 6)
//   PO(t)  <- FH1>=t+1; [t>=16] FZO >= t-15                   (po1 ring 16)
//   H2U(s) <- FP2>=s+1; [s>=1] FPG>=s, FH2>=s; [s>=16] FZO>=s-15 (h2 ring 16)
//   ZO(ot) <- FH2>=ot+1, FPO>=ot+1
__global__ void __launch_bounds__(256, 1) rnn_kernel(RP p) {
  __shared__ short As[64 * RS];     // 134144 B (two 32-row chunks)
  __shared__ float zbuf[2048];      // 8 KB H2U z-exchange
  const int tid = threadIdx.x;
  const int lane = tid & 63;
  const int wv = tid >> 6;
  const int lm = lane & 15;
  const int q = lane >> 4;
  const int bid = blockIdx.x;

  const size_t HS = (size_t)Bb * Hh;
  const f32x4 z4 = {0.f, 0.f, 0.f, 0.f};
  int4 w[32];                       // this wave's weight slice (128 VGPR)

  if (bid < 64) {                      // ===== H1: 4rg x 16cg, 32r x 64c =====
    const int g = bid;
    const int mb = (g >> 4) * 32, cb = (g & 15) * 64;
    const int cw = cb + wv * 16;
    loadW(w, p.whh1 + (size_t)cw * Hh, Hh, lm, q);
    for (int t = 0; t < Tt; ++t) {
      short prs[2][4];
      const short* pr = p.prex + (size_t)t * HS;
#pragma unroll
      for (int rf = 0; rf < 2; ++rf)
#pragma unroll
        for (int r = 0; r < 4; ++r)
          prs[rf][r] = pr[(size_t)(mb + rf * 16 + q * 4 + r) * Hh + cw + lm];
      if (tid < 64) {
        if (t >= 1) poll_ge(p.flags, FH1, 63, (unsigned)t);
        if (t >= 8) {
          poll_ge(p.flags, FP2, 31, (unsigned)(t - 7));
          poll_ge(p.flags, FPG, 31, (unsigned)(t - 7));
          poll_ge(p.flags, FPO, 3,  (unsigned)(t - 7));
        }
      }
      __syncthreads();
      const short* h1prev = p.h1ring + (size_t)((t + R_H1 - 1) % R_H1) * HS;
      stage_chunk(As, h1prev + (size_t)mb * Hh, tid);
      __syncthreads();
      f32x4 a0 = z4, a1 = z4;
      passW2(As, lm, q, w, a0, a1);
      short* h1out = p.h1ring + (size_t)(t % R_H1) * HS;
#pragma unroll
      for (int rf = 0; rf < 2; ++rf)
#pragma unroll
        for (int r = 0; r < 4; ++r) {
          const int row = mb + rf * 16 + q * 4 + r;
          const float z = rf ? a1[r] : a0[r];
          const short hv = f2bf(tanhf(z + bf2f(prs[rf][r])));
          ST_BF16_PAIR(h1out, row, cw + lm, hv);
        }
      POST_FLAG(FH1 + g, t + 1);
    }
  } else if (bid < 128) {              // ===== P2 / PG: 2rg x 16cg, 64r x 64c =====
    const bool isP2 = (bid < 96);
    const int g = isP2 ? (bid - 64) : (bid - 96);
    const int mb = (g >> 4) * 64, cb = (g & 15) * 64;
    const int cw = cb + wv * 16;
    float bias;
    if (isP2) {
      bias = p.b_ih2[cw + lm] + p.b_hh2[cw + lm];
      loadW(w, p.wih2 + (size_t)cw * Hh, Hh, lm, q);
    } else {
      bias = p.bg[cw + lm];
      loadW(w, p.wg + (size_t)cw * (2 * Hh), 2 * Hh, lm, q);
    }
    const int fbase = isP2 ? FP2 : FPG;
    const int fslot = fbase + g;
    for (int t = 0; t < Tt; ++t) {
      if (tid < 64) {
        poll_ge(p.flags, FH1, 63, (unsigned)(t + 1));
        if (t >= R_PP) poll_ge(p.flags, FH2, 63, (unsigned)(t - (isP2 ? 5 : 4)));
      }
      __syncthreads();
      const short* h1cur = p.h1ring + (size_t)(t % R_H1) * HS;
      stage_chunk(As, h1cur + (size_t)mb * Hh, tid);
      stage_chunk(As + 32 * RS, h1cur + (size_t)(mb + 32) * Hh, tid);
      __syncthreads();
      f32x4 acc[4];
      acc[0] = acc[1] = acc[2] = acc[3] = (f32x4){bias, bias, bias, bias};
      passW2(As, lm, q, w, acc[0], acc[1]);
      passW2(As + 32 * RS, lm, q, w, acc[2], acc[3]);
      float* dst = (isP2 ? p.pre2f : p.pg1f) + (size_t)(t % R_PP) * HS;
#pragma unroll
      for (int rf = 0; rf < 4; ++rf)
#pragma unroll
        for (int r = 0; r < 4; ++r) {
          const int row = mb + rf * 16 + q * 4 + r;
          stf(dst + (size_t)row * Hh + cw + lm, acc[rf][r]);
        }
      POST_FLAG(fslot, t + 1);
    }
  } else if (bid < 192) {              // ===== H2U: 2rg x 32cg, 64r x 32c =====
    const int g = bid - 128;
    const int mb = (g >> 5) * 64, cb = (g & 31) * 32;
    const int m = wv >> 1;             // 0: z2 (whh2), 1: zg (wg2)
    const int ch = wv & 1;             // col half
    const int cw = cb + ch * 16;
    if (m == 0) loadW(w, p.whh2 + (size_t)cw * Hh, Hh, lm, q);
    else        loadW(w, p.wg + Hh + (size_t)cw * (2 * Hh), 2 * Hh, lm, q);
    for (int s = 0; s < Tt; ++s) {
      if (tid < 64) {
        poll_ge(p.flags, FP2, 31, (unsigned)(s + 1));
        if (s >= 1) {
          poll_ge(p.flags, FPG, 31, (unsigned)s);
          poll_ge(p.flags, FH2, 63, (unsigned)s);
        }
        if (s >= R_H2) poll_ge(p.flags, FZO, 3, (unsigned)(s - 15));
      }
      __syncthreads();
      float p2v[4][4], pg1v[4][4], hpv[4][4];
      if (m == 0) {
        const float* pre2s = p.pre2f + (size_t)(s % R_PP) * HS;
        const float* pg1s  = p.pg1f + (size_t)((s + R_PP - 1) % R_PP) * HS;
#pragma unroll
        for (int rf = 0; rf < 4; ++rf)
#pragma unroll
          for (int r = 0; r < 4; ++r) {
            const size_t idx = (size_t)(mb + rf * 16 + q * 4 + r) * Hh + cw + lm;
            p2v[rf][r] = ldf(pre2s + idx);
            pg1v[rf][r] = (s > 0) ? ldf(pg1s + idx) : 0.f;
            hpv[rf][r] = p.h2f[idx];     // block-local plain RW
          }
      }
      const short* h2prev = p.h2ring + (size_t)((s + R_H2 - 1) % R_H2) * HS;
      stage_chunk(As, h2prev + (size_t)mb * Hh, tid);
      stage_chunk(As + 32 * RS, h2prev + (size_t)(mb + 32) * Hh, tid);
      __syncthreads();
      f32x4 acc[4];
      acc[0] = acc[1] = acc[2] = acc[3] = z4;
      passW2(As, lm, q, w, acc[0], acc[1]);
      passW2(As + 32 * RS, lm, q, w, acc[2], acc[3]);
      if (m == 1) {                    // publish zg to wave (wv-2)
        float* zb = zbuf + ch * 1024;
#pragma unroll
        for (int rf = 0; rf < 4; ++rf)
#pragma unroll
          for (int r = 0; r < 4; ++r)
            zb[(rf * 4 + r) * 64 + lane] = acc[rf][r];
      }
      __syncthreads();
      if (m == 0) {
        const float* zb = zbuf + ch * 1024;
        short* h2out = p.h2ring + (size_t)(s % R_H2) * HS;
#pragma unroll
        for (int rf = 0; rf < 4; ++rf)
#pragma unroll
          for (int r = 0; r < 4; ++r) {
            const int row = mb + rf * 16 + q * 4 + r;
            const size_t idx = (size_t)row * Hh + cw + lm;
            const float zg = zb[(rf * 4 + r) * 64 + lane];
            const float u = (s == 0) ? 1.f
                : 1.f / (1.f + expf(-(zg + pg1v[rf][r])));
            const float hn = tanhf(acc[rf][r] + p2v[rf][r]);
            const float nv = fmaf(u, hn - hpv[rf][r], hpv[rf][r]);
            p.h2f[idx] = nv;
            const short hv = f2bf(nv);
            ST_BF16_PAIR(h2out, row, cw + lm, hv);
          }
      }
      POST_FLAG(FH2 + g, s + 1);
    }
  } else if (bid < 196) {              // ===== PO: 4rg, 32r x 64c =====
    const int g = bid - 192;
    const int mb = g * 32;
    const int cw = wv * 16;
    const float bias = p.bo1[cw + lm];
    loadW(w, p.wo1 + (size_t)cw * Hh, Hh, lm, q);
    for (int t = 0; t < Tt; ++t) {
      if (tid < 64) {
        poll_ge(p.flags, FH1, 63, (unsigned)(t + 1));
        if (t >= R_PO) poll_ge(p.flags, FZO, 3, (unsigned)(t - 15));
      }
      __syncthreads();
      const short* h1cur = p.h1ring + (size_t)(t % R_H1) * HS;
      stage_chunk(As, h1cur + (size_t)mb * Hh, tid);
      __syncthreads();
      f32x4 a0 = {bias, bias, bias, bias}, a1 = a0;
      passW2(As, lm, q, w, a0, a1);
      float* dst = p.po1f + (size_t)(t % R_PO) * (Bb * Oo);
#pragma unroll
      for (int rf = 0; rf < 2; ++rf)
#pragma unroll
        for (int r = 0; r < 4; ++r) {
          const int row = mb + rf * 16 + q * 4 + r;
          const float z = rf ? a1[r] : a0[r];
          stf(dst + (size_t)row * Oo + cw + lm, tanhf(z));
        }
      POST_FLAG(FPO + g, t + 1);
    }
  } else {                             // ===== ZO: 4rg, 32r x 64c =====
    const int g = bid - 196;
    const int mb = g * 32;
    const int cw = wv * 16;
    const float bias = p.bo2[cw + lm];
    loadW(w, p.wo2 + (size_t)cw * Hh, Hh, lm, q);
    for (int ot = 0; ot < Tt; ++ot) {
      if (tid < 64) {
        poll_ge(p.flags, FH2, 63, (unsigned)(ot + 1));
        poll_ge(p.flags, FPO, 3,  (unsigned)(ot + 1));
      }
      __syncthreads();
      float pv[2][4];
      const float* po1s = p.po1f + (size_t)(ot % R_PO) * (Bb * Oo);
#pragma unroll
      for (int rf = 0; rf < 2; ++rf)
#pragma unroll
        for (int r = 0; r < 4; ++r)
          pv[rf][r] = ldf(po1s + (size_t)(mb + rf * 16 + q * 4 + r) * Oo + cw + lm);
      const short* h2cur = p.h2ring + (size_t)(ot % R_H2) * HS;
      stage_chunk(As, h2cur + (size_t)mb * Hh, tid);
      __syncthreads();
      f32x4 a0 = {bias, bias, bias, bias}, a1 = a0;
      passW2(As, lm, q, w, a0, a1);
#pragma unroll
      for (int rf = 0; rf < 2; ++rf)
#pragma unroll
        for (int r = 0; r < 4; ++r) {
          const int row = mb + rf * 16 + q * 4 + r;
          const float z = rf ? a1[r] : a0[r];
          p.out[(size_t)row * (Tt * Oo) + (size_t)ot * Oo + cw + lm] =
              pv[rf][r] + tanhf(z);
        }
      POST_FLAG(FZO + g, ot + 1);
    }
  }
}

// pre_x[t][b][j] = x[b,t,:] @ W_ih1[j,:] + b_ih1[j] + b_hh1[j]  (stored bf16)
__global__ void __launch_bounds__(256) prex_kernel(
    const float* __restrict__ x, const float* __restrict__ wih1,
    const float* __restrict__ b_ih1, const float* __restrict__ b_hh1,
    short* __restrict__ prex) {
  const int tid = threadIdx.x;
  const int lane = tid & 63;
  const int wv = tid >> 6;
  const int lm = lane & 15;
  const int q = lane >> 4;
  const int bm = blockIdx.x >> 4;
  const int bn = blockIdx.x & 15;
  const int rowbase = bm * 64;
  const int col = bn * 64 + wv * 16 + lm;

  const f32x4 z4 = {0.f, 0.f, 0.f, 0.f};
  f32x4 acc[4];
#pragma unroll
  for (int mt = 0; mt < 4; ++mt) acc[mt] = z4;

#pragma unroll
  for (int kc = 0; kc < 2; ++kc) {
    const float* bp = wih1 + col * 64 + kc * 32 + q * 8;
    bf16x8 bf;
#pragma unroll
    for (int j = 0; j < 8; ++j) bf[j] = f2bf(bp[j]);
#pragma unroll
    for (int mt = 0; mt < 4; ++mt) {
      const float* ap = x + (size_t)(rowbase + mt * 16 + lm) * 64 + kc * 32 + q * 8;
      bf16x8 af;
#pragma unroll
      for (int j = 0; j < 8; ++j) af[j] = f2bf(ap[j]);
      acc[mt] = __builtin_amdgcn_mfma_f32_16x16x32_bf16(af, bf, acc[mt], 0, 0, 0);
    }
  }
  const float bia = b_ih1[col] + b_hh1[col];
#pragma unroll
  for (int mt = 0; mt < 4; ++mt) {
#pragma unroll
    for (int r = 0; r < 4; ++r) {
      const int row = rowbase + mt * 16 + q * 4 + r;  // row = b*256 + t
      const int b  = row >> 8;
      const int tt = row & 255;
      prex[((size_t)tt * Bb + b) * Hh + col] = f2bf(acc[mt][r] + bia);
    }
  }
}

__global__ void conv_kernel(const float* __restrict__ s, short* __restrict__ d, int n) {
  int i = blockIdx.x * blockDim.x + threadIdx.x;
  const int stride = gridDim.x * blockDim.x;
  for (; i < n; i += stride) d[i] = f2bf(s[i]);
}

__global__ void init_kernel(short* h1ring, short* h2ring,
                            float* h2f, unsigned* flags) {
  const int i = blockIdx.x * blockDim.x + threadIdx.x;  // exactly 128*1024
  const size_t HS = (size_t)Bb * Hh;
  h1ring[(size_t)(R_H1 - 1) * HS + i] = 0;   // h1(-1) slot
  h2ring[(size_t)(R_H2 - 1) * HS + i] = 0;   // h2(-1) slot
  h2f[i] = 0.f;
  if (i < 256) flags[i * FLAG_STRIDE] = 0u;
}

extern "C" void kernel_launch(void* const* d_in, const int* in_sizes, int n_in,
                              void* d_out, int out_size, void* d_ws, size_t ws_size,
                              hipStream_t stream) {
  (void)in_sizes; (void)n_in; (void)out_size; (void)ws_size;
  const float* x      = (const float*)d_in[0];
  const float* W_ih1  = (const float*)d_in[1];
  const float* b_ih1  = (const float*)d_in[2];
  const float* W_hh1  = (const float*)d_in[3];
  const float* b_hh1  = (const float*)d_in[4];
  const float* W_ih2  = (const float*)d_in[5];
  const float* b_ih2  = (const float*)d_in[6];
  const float* W_hh2  = (const float*)d_in[7];
  const float* b_hh2  = (const float*)d_in[8];
  const float* Wg     = (const float*)d_in[9];
  const float* bg     = (const float*)d_in[10];
  const float* Wo1    = (const float*)d_in[11];
  const float* bo1    = (const float*)d_in[12];
  const float* Wo2    = (const float*)d_in[13];
  const float* bo2    = (const float*)d_in[14];

  char* ws = (char*)d_ws;
  size_t off = 0;
  auto alloc = [&](size_t bytes) -> void* {
    void* ptr = ws + off;
    off += (bytes + 255) & ~(size_t)255;
    return ptr;
  };
  short* whh1 = (short*)alloc((size_t)Hh * Hh * 2);
  short* wih2 = (short*)alloc((size_t)Hh * Hh * 2);
  short* whh2 = (short*)alloc((size_t)Hh * Hh * 2);
  short* wg   = (short*)alloc((size_t)Hh * 2 * Hh * 2);
  short* wo1  = (short*)alloc((size_t)Oo * Hh * 2);
  short* wo2  = (short*)alloc((size_t)Oo * Hh * 2);
  short* prex = (short*)alloc((size_t)Bb * Tt * Hh * 2);
  short* h1ring = (short*)alloc((size_t)R_H1 * Bb * Hh * 2);
  short* h2ring = (short*)alloc((size_t)R_H2 * Bb * Hh * 2);
  float* h2f  = (float*)alloc((size_t)Bb * Hh * 4);
  float* pre2f= (float*)alloc((size_t)R_PP * Bb * Hh * 4);
  float* pg1f = (float*)alloc((size_t)R_PP * Bb * Hh * 4);
  float* po1f = (float*)alloc((size_t)R_PO * Bb * Oo * 4);
  unsigned* flags = (unsigned*)alloc(256 * FLAG_STRIDE * 4);   // 32 KB

  conv_kernel<<<1024, 256, 0, stream>>>(W_hh1, whh1, Hh * Hh);
  conv_kernel<<<1024, 256, 0, stream>>>(W_ih2, wih2, Hh * Hh);
  conv_kernel<<<1024, 256, 0, stream>>>(W_hh2, whh2, Hh * Hh);
  conv_kernel<<<2048, 256, 0, stream>>>(Wg,    wg,   Hh * 2 * Hh);
  conv_kernel<<<256,  256, 0, stream>>>(Wo1,   wo1,  Oo * Hh);
  conv_kernel<<<256,  256, 0, stream>>>(Wo2,   wo2,  Oo * Hh);
  init_kernel<<<512, 256, 0, stream>>>(h1ring, h2ring, h2f, flags);
  prex_kernel<<<8192, 256, 0, stream>>>(x, W_ih1, b_ih1, b_hh1, prex);

  RP p;
  p.h1ring = h1ring; p.h2ring = h2ring;
  p.h2f = h2f; p.pre2f = pre2f; p.pg1f = pg1f; p.po1f = po1f;
  p.prex = prex;
  p.whh1 = whh1; p.wih2 = wih2; p.whh2 = whh2;
  p.wg = wg; p.wo1 = wo1; p.wo2 = wo2;
  p.b_ih2 = b_ih2; p.b_hh2 = b_hh2;
  p.bg = bg; p.bo1 = bo1; p.bo2 = bo2;
  p.out = (float*)d_out;
  p.flags = flags;

  rnn_kernel<<<NBLK, 256, 0, stream>>>(p);
}